// Round 1
// baseline (2889.162 us; speedup 1.0000x reference)
//
#include <hip/hip_runtime.h>

// PointNet++ SA module: FPS -> ball query (K nearest within R) -> gather ->
// 3-layer MLP -> masked max aggregation.
//
// B=4 batches, NP=8192 pts, MP=2048 centers/batch, K=64, R=0.2, D_IN=32.
// d_out = [x_out (8192*128) | pos_out (8192*3) | batch_out (8192)] as fp32.
//
// ws layout (bytes):
//   P1  : 0        .. 8388608   (32768 x 64 fp32)  = x @ W1[0:32]
//   W2T : 8388608  .. 8404992   (64x64 fp32, transposed)
//   W3T : 8404992  .. 8437760   (128x64 fp32, transposed)
//   nbr : 8437760  .. 10534912  (8192 x 64 int32, -1 = invalid)

#define BATCH 4
#define NP 8192
#define MP 2048
#define KNN 64
#define DIN 32

// One v_max_f32 + DPP step: disabled/invalid source lanes fall back to `old`
// (= v itself, the fmax identity here).  Pure VALU — no LDS latency.
#define DPP_FMAX(v, ctrl)                                                     \
  {                                                                           \
    int _t = __builtin_amdgcn_update_dpp(__float_as_int(v),                   \
                                         __float_as_int(v), (ctrl), 0xF,      \
                                         0xF, false);                         \
    (v) = fmaxf((v), __int_as_float(_t));                                     \
  }

// Packed fp32 (2 points / instruction).  Per-element semantics identical to
// the scalar v_add/v_mul/v_fma the compiler emits for the unpacked form, so
// FPS selection is bit-identical to the previously verified kernel.
typedef float v2f __attribute__((ext_vector_type(2)));

__device__ __forceinline__ v2f pk_add(v2f a, v2f b) {
  v2f r;
  asm("v_pk_add_f32 %0, %1, %2" : "=v"(r) : "v"(a), "v"(b));
  return r;
}
__device__ __forceinline__ v2f pk_mul(v2f a, v2f b) {
  v2f r;
  asm("v_pk_mul_f32 %0, %1, %2" : "=v"(r) : "v"(a), "v"(b));
  return r;
}
__device__ __forceinline__ v2f pk_fma(v2f a, v2f b, v2f c) {
  v2f r;
  asm("v_pk_fma_f32 %0, %1, %2, %3" : "=v"(r) : "v"(a), "v"(b), "v"(c));
  return r;
}

// ---------------------------------------------------------------- FPS ------
// One block per batch, 512 threads (8 waves), 16 points/thread in VGPRs
// (packed as 8 v2f per coordinate).  VALU-throughput-bound on its 4 CUs, so
// the optimization target is issued instructions per serial iteration:
//   - packed pk_add/pk_mul/pk_fma distance update: 9 instr / 2 points
//     (exact same per-element fp ops: sub, fma(dx,dx, mul(dy,dy)), fma(dz,..))
//   - owner lane stores ONE u64 {d2_bits<<32 | global_idx} to its parity
//     slot; no float4 coord staging, no 21-cndmask coord pick.
//   - stage-2: ONE ds_read_b64 of 8 slots, 3-step DPP max, ballot->first wid,
//     winner index via readlane, coords via wave-uniform (scalar) load from
//     pos[] — identical memory values as before.
// Tie-break = first global index, exactly as jnp.argmax: global idx order is
// (wid, lane, k) with j = tid*16+k; ballot-ctz picks first lane, descending
// overwrite picks first k, ballot-ctz on slots picks first wid.
__global__ __launch_bounds__(512) void fps_k(const float* __restrict__ pos,
                                             float* __restrict__ pout,
                                             float* __restrict__ bout)
{
  const int b = blockIdx.x;
  const int tid = threadIdx.x;
  const int lane = tid & 63, wid = tid >> 6;
  const float* __restrict__ pb = pos + (size_t)b * NP * 3;
  const int base = tid * 16;

  // batch_out as float values (harness reads d_out as one fp32 buffer)
#pragma unroll
  for (int q = 0; q < 4; q++) bout[b * MP + q * 512 + tid] = (float)b;

  // --- load 16 points (48 contiguous floats) via 12 float4 loads ---
  float t[48];
  const float4* __restrict__ pv = (const float4*)(pb + (size_t)base * 3);
#pragma unroll
  for (int q = 0; q < 12; q++) *(float4*)&t[q * 4] = pv[q];

  v2f px[8], py[8], pz[8], d[8];
#pragma unroll
  for (int j = 0; j < 8; j++) {
    px[j].x = t[6 * j + 0]; py[j].x = t[6 * j + 1]; pz[j].x = t[6 * j + 2];
    px[j].y = t[6 * j + 3]; py[j].y = t[6 * j + 4]; pz[j].y = t[6 * j + 5];
  }

  const float c0x = pb[0], c0y = pb[1], c0z = pb[2];
  if (tid == 0) {  // sel[0] = 0
    pout[(size_t)b * MP * 3 + 0] = c0x;
    pout[(size_t)b * MP * 3 + 1] = c0y;
    pout[(size_t)b * MP * 3 + 2] = c0z;
  }

  // initial distances to center 0 (sub == add of negated center, exact)
  v2f cxn = {-c0x, -c0x}, cyn = {-c0y, -c0y}, czn = {-c0z, -c0z};
  float bv = -1.f;
#pragma unroll
  for (int j = 0; j < 8; j++) {
    v2f dx = pk_add(px[j], cxn);
    v2f dy = pk_add(py[j], cyn);
    v2f dz = pk_add(pz[j], czn);
    v2f nd = pk_fma(dx, dx, pk_mul(dy, dy));
    nd = pk_fma(dz, dz, nd);
    d[j] = nd;
    bv = fmaxf(bv, fmaxf(nd.x, nd.y));
  }

  // double-buffered parity slots: one barrier per iteration suffices
  __shared__ unsigned long long slt[2][8];

  for (int i = 1; i < MP; i++) {
    // --- 64-lane max, pure VALU (DPP): result lands in lane 63 ---
    float v = bv;
    DPP_FMAX(v, 0x111);   // row_shr:1
    DPP_FMAX(v, 0x112);   // row_shr:2
    DPP_FMAX(v, 0x114);   // row_shr:4
    DPP_FMAX(v, 0x118);   // row_shr:8
    DPP_FMAX(v, 0x142);   // row_bcast:15
    DPP_FMAX(v, 0x143);   // row_bcast:31
    const float wmax =
        __int_as_float(__builtin_amdgcn_readlane(__float_as_int(v), 63));

    // owner lane = first lane holding wmax; it writes {value, global idx}
    const unsigned long long m = __ballot(bv == wmax);
    const int src = (int)__builtin_ctzll(m);
    const int p = i & 1;
    if (lane == src) {
      int ks = 15;
#pragma unroll
      for (int k = 14; k >= 0; k--) {        // descending => first k wins
        float dv = (k & 1) ? d[k >> 1].y : d[k >> 1].x;
        if (dv == wmax) ks = k;              // cndmask with inline-const k
      }
      slt[p][wid] = ((unsigned long long)__float_as_uint(wmax) << 32)
                    | (unsigned)(base + ks);
    }
    __syncthreads();

    // --- 8-slot argmax (first-wid tie-break), ONE LDS round trip ---
    const unsigned long long kv = slt[p][lane & 7];  // broadcast reads
    const float v2 = __uint_as_float((unsigned)(kv >> 32));
    float v2r = v2;
    DPP_FMAX(v2r, 0x111);
    DPP_FMAX(v2r, 0x112);
    DPP_FMAX(v2r, 0x114);                    // lane 7 = max of slots 0..7
    const float mv =
        __int_as_float(__builtin_amdgcn_readlane(__float_as_int(v2r), 7));
    const unsigned long long m2 = __ballot(v2 == mv);
    const int mw = (int)__builtin_ctzll(m2);          // first wid among ties
    const int js = __builtin_amdgcn_readlane((int)(unsigned)kv, mw);
    // wave-uniform index -> scalar-cache loads of the winner's coords
    const float ncx = pb[js * 3 + 0];
    const float ncy = pb[js * 3 + 1];
    const float ncz = pb[js * 3 + 2];

    if (tid == 0) {
      pout[((size_t)b * MP + i) * 3 + 0] = ncx;
      pout[((size_t)b * MP + i) * 3 + 1] = ncy;
      pout[((size_t)b * MP + i) * 3 + 2] = ncz;
    }

    // fused packed min-update + local value max for next iteration
    cxn = (v2f){-ncx, -ncx};
    cyn = (v2f){-ncy, -ncy};
    czn = (v2f){-ncz, -ncz};
    bv = -1.f;
#pragma unroll
    for (int j = 0; j < 8; j++) {
      v2f dx = pk_add(px[j], cxn);
      v2f dy = pk_add(py[j], cyn);
      v2f dz = pk_add(pz[j], czn);
      v2f nd = pk_fma(dx, dx, pk_mul(dy, dy));
      nd = pk_fma(dz, dz, nd);
      v2f dn;
      dn.x = fminf(d[j].x, nd.x);
      dn.y = fminf(d[j].y, nd.y);
      d[j] = dn;
      bv = fmaxf(bv, fmaxf(dn.x, dn.y));
    }
  }
}

// ---------------------------------------------------------- ball query -----
// One wave (64-thread block) per center. Candidates (d2<=R2) compacted to
// LDS as u64 keys (d2_bits<<32 | idx); 64 rounds of wave-argmin reproduce
// lax.top_k's stable (d2 asc, idx asc) selection exactly.
__global__ __launch_bounds__(64) void ballq_k(const float* __restrict__ pos,
                                              const float* __restrict__ pout,
                                              int* __restrict__ nbr)
{
  const int wg = blockIdx.x;       // center id 0..8191
  const int lane = threadIdx.x;
  const int b = wg >> 11;
  const float* __restrict__ pb = pos + (size_t)b * NP * 3;
  const float cx = pout[(size_t)wg * 3 + 0];
  const float cy = pout[(size_t)wg * 3 + 1];
  const float cz = pout[(size_t)wg * 3 + 2];
  const float R2 = (float)(0.2 * 0.2);   // matches JAX weak-type promotion exactly

  __shared__ unsigned long long cand[1024];
  int cnt = 0;
  for (int basej = 0; basej < NP; basej += 64) {
    const int j = basej + lane;
    float dx = pb[j * 3 + 0] - cx;
    float dy = pb[j * 3 + 1] - cy;
    float dz = pb[j * 3 + 2] - cz;
    float d2 = dx * dx + dy * dy + dz * dz;
    bool in = (d2 <= R2);
    unsigned long long mb = __ballot(in);
    int pre = (int)__popcll(mb & ((1ull << lane) - 1ull));
    int slot = cnt + pre;
    if (in && slot < 1024)
      cand[slot] = ((unsigned long long)__float_as_uint(d2) << 32) | (unsigned int)j;
    cnt += (int)__popcll(mb);
  }
  if (cnt > 1024) cnt = 1024;   // unreachable for this data (max ~360)

  int myout = -1;
  for (int r = 0; r < KNN; r++) {
    unsigned long long v = ~0ull; int slot = -1;
    for (int s = lane; s < cnt; s += 64) {
      unsigned long long c = cand[s];
      if (c < v) { v = c; slot = s; }
    }
#pragma unroll
    for (int off = 1; off < 64; off <<= 1) {
      unsigned long long ov = __shfl_xor(v, off);
      int os = __shfl_xor(slot, off);
      if (ov < v) { v = ov; slot = os; }
    }
    if (lane == r) myout = (v == ~0ull) ? -1 : (int)(v & 0xffffffffu);
    if (lane == 0 && slot >= 0) cand[slot] = ~0ull;  // remove winner
    __syncthreads();
  }
  nbr[(size_t)wg * KNN + lane] = myout;
}

// --------------------------------------------------- P1 = x @ W1[0:32] -----
__global__ __launch_bounds__(64) void p1_k(const float* __restrict__ x,
                                           const float* __restrict__ W1,
                                           float* __restrict__ P1)
{
  const int j = blockIdx.x;          // global point row 0..32767
  const int c = threadIdx.x;
  const float* __restrict__ xr = x + (size_t)j * DIN;
  float acc = 0.f;
#pragma unroll
  for (int k = 0; k < DIN; k++) acc += xr[k] * W1[k * 64 + c];
  P1[(size_t)j * 64 + c] = acc;
}

// ------------------------------------------------------ weight transposes --
__global__ __launch_bounds__(256) void tw_k(const float* __restrict__ W2,
                                            const float* __restrict__ W3,
                                            float* __restrict__ W2T,
                                            float* __restrict__ W3T)
{
  int e = blockIdx.x * 256 + threadIdx.x;
  if (e < 64 * 64) {
    int c = e >> 6, k = e & 63;
    W2T[e] = W2[k * 64 + c];
  } else {
    int e2 = e - 64 * 64;
    if (e2 < 128 * 64) {
      int c = e2 >> 6, k = e2 & 63;
      W3T[e2] = W3[k * 128 + c];
    }
  }
}

// ------------------------------------------------------- MLP + max agg -----
// One wave (64-thread block) per center, lane = neighbor slot.
// h1 in VGPRs; h2 staged in LDS at stride 68 floats (stride 64 => 64-way
// bank conflict; 68 => conflict-free b128 pattern). Weight reads use
// wave-uniform indices -> scalar (SGPR) loads.
__global__ __launch_bounds__(64) void mlp_k(const float* __restrict__ pos,
    const float* __restrict__ P1, const float* __restrict__ W1,
    const float* __restrict__ b1, const float* __restrict__ W2T,
    const float* __restrict__ b2, const float* __restrict__ W3T,
    const float* __restrict__ b3, const int* __restrict__ nbr,
    const float* __restrict__ pout, float* __restrict__ xout)
{
  __shared__ __align__(16) float h2s[64 * 68];
  const int wg = blockIdx.x;
  const int lane = threadIdx.x;
  const int b = wg >> 11;
  const int idx = nbr[(size_t)wg * KNN + lane];
  const bool valid = idx >= 0;
  const int j = valid ? idx : 0;
  const float cx = pout[(size_t)wg * 3 + 0];
  const float cy = pout[(size_t)wg * 3 + 1];
  const float cz = pout[(size_t)wg * 3 + 2];
  const float* __restrict__ pj = pos + ((size_t)b * NP + j) * 3;
  const float rx = pj[0] - cx, ry = pj[1] - cy, rz = pj[2] - cz;
  const float* __restrict__ p1r =
      (const float*)__builtin_assume_aligned(P1 + ((size_t)b * NP + j) * 64, 16);

  // layer 1: h1 = relu(P1[j] + rel @ W1[32:35] + b1)   (64 VGPRs)
  float h1[64];
#pragma unroll
  for (int k = 0; k < 64; k++) {
    float v = p1r[k] + rx * W1[32 * 64 + k] + ry * W1[33 * 64 + k]
                     + rz * W1[34 * 64 + k] + b1[k];
    h1[k] = fmaxf(v, 0.f);
  }

  // layer 2: h2 = relu(h1 @ W2 + b2) -> LDS
  for (int c4 = 0; c4 < 16; c4++) {
    float a0 = b2[c4 * 4 + 0], a1 = b2[c4 * 4 + 1];
    float a2 = b2[c4 * 4 + 2], a3 = b2[c4 * 4 + 3];
    const float* __restrict__ w0 = W2T + (c4 * 4 + 0) * 64;
    const float* __restrict__ w1 = W2T + (c4 * 4 + 1) * 64;
    const float* __restrict__ w2 = W2T + (c4 * 4 + 2) * 64;
    const float* __restrict__ w3 = W2T + (c4 * 4 + 3) * 64;
#pragma unroll
    for (int k = 0; k < 64; k++) {
      a0 += h1[k] * w0[k]; a1 += h1[k] * w1[k];
      a2 += h1[k] * w2[k]; a3 += h1[k] * w3[k];
    }
    float4 q;
    q.x = fmaxf(a0, 0.f); q.y = fmaxf(a1, 0.f);
    q.z = fmaxf(a2, 0.f); q.w = fmaxf(a3, 0.f);
    *(float4*)&h2s[lane * 68 + c4 * 4] = q;
  }

  // layer 3 + per-channel max over neighbors (relu>=0 and center is always a
  // valid neighbor, so invalid lanes contributing 0 == reference -BIG mask)
  float4 keep = make_float4(0.f, 0.f, 0.f, 0.f);
  const float* __restrict__ h2p = &h2s[lane * 68];
  for (int c4 = 0; c4 < 32; c4++) {
    float a0 = b3[c4 * 4 + 0], a1 = b3[c4 * 4 + 1];
    float a2 = b3[c4 * 4 + 2], a3 = b3[c4 * 4 + 3];
    const float* __restrict__ w0 = W3T + (c4 * 4 + 0) * 64;
    const float* __restrict__ w1 = W3T + (c4 * 4 + 1) * 64;
    const float* __restrict__ w2 = W3T + (c4 * 4 + 2) * 64;
    const float* __restrict__ w3 = W3T + (c4 * 4 + 3) * 64;
#pragma unroll
    for (int k4 = 0; k4 < 16; k4++) {
      float4 h = *(const float4*)&h2p[k4 * 4];
      a0 += h.x * w0[k4 * 4 + 0]; a0 += h.y * w0[k4 * 4 + 1];
      a0 += h.z * w0[k4 * 4 + 2]; a0 += h.w * w0[k4 * 4 + 3];
      a1 += h.x * w1[k4 * 4 + 0]; a1 += h.y * w1[k4 * 4 + 1];
      a1 += h.z * w1[k4 * 4 + 2]; a1 += h.w * w1[k4 * 4 + 3];
      a2 += h.x * w2[k4 * 4 + 0]; a2 += h.y * w2[k4 * 4 + 1];
      a2 += h.z * w2[k4 * 4 + 2]; a2 += h.w * w2[k4 * 4 + 3];
      a3 += h.x * w3[k4 * 4 + 0]; a3 += h.y * w3[k4 * 4 + 1];
      a3 += h.z * w3[k4 * 4 + 2]; a3 += h.w * w3[k4 * 4 + 3];
    }
    a0 = valid ? fmaxf(a0, 0.f) : 0.f;
    a1 = valid ? fmaxf(a1, 0.f) : 0.f;
    a2 = valid ? fmaxf(a2, 0.f) : 0.f;
    a3 = valid ? fmaxf(a3, 0.f) : 0.f;
#pragma unroll
    for (int off = 1; off < 64; off <<= 1) {
      a0 = fmaxf(a0, __shfl_xor(a0, off));
      a1 = fmaxf(a1, __shfl_xor(a1, off));
      a2 = fmaxf(a2, __shfl_xor(a2, off));
      a3 = fmaxf(a3, __shfl_xor(a3, off));
    }
    if (lane == c4) { keep.x = a0; keep.y = a1; keep.z = a2; keep.w = a3; }
  }
  if (lane < 32)
    *(float4*)&xout[(size_t)wg * 128 + lane * 4] = keep;
}

// --------------------------------------------------------------- launch ----
extern "C" void kernel_launch(void* const* d_in, const int* in_sizes, int n_in,
                              void* d_out, int out_size, void* d_ws, size_t ws_size,
                              hipStream_t stream)
{
  const float* x   = (const float*)d_in[0];
  const float* pos = (const float*)d_in[1];
  // d_in[2] = batch (unused; layout is implicit)
  const float* W1 = (const float*)d_in[3];
  const float* b1 = (const float*)d_in[4];
  const float* W2 = (const float*)d_in[5];
  const float* b2 = (const float*)d_in[6];
  const float* W3 = (const float*)d_in[7];
  const float* b3 = (const float*)d_in[8];

  float* out  = (float*)d_out;
  float* xout = out;                      // 8192*128
  float* pout = out + 8192 * 128;         // 8192*3
  float* bout = out + 8192 * 128 + 8192 * 3;  // 8192

  char* ws = (char*)d_ws;
  float* P1  = (float*)ws;
  float* W2T = (float*)(ws + 8388608);
  float* W3T = (float*)(ws + 8404992);
  int*   nbr = (int*)(ws + 8437760);

  fps_k<<<dim3(BATCH), dim3(512), 0, stream>>>(pos, pout, bout);
  p1_k<<<dim3(BATCH * NP), dim3(64), 0, stream>>>(x, W1, P1);
  tw_k<<<dim3(48), dim3(256), 0, stream>>>(W2, W3, W2T, W3T);
  ballq_k<<<dim3(BATCH * MP), dim3(64), 0, stream>>>(pos, pout, nbr);
  mlp_k<<<dim3(BATCH * MP), dim3(64), 0, stream>>>(pos, P1, W1, b1, W2T, b2,
                                                   W3T, b3, nbr, pout, xout);
}

// Round 2
// 2554.229 us; speedup vs baseline: 1.1311x; 1.1311x over previous
//
#include <hip/hip_runtime.h>

// PointNet++ SA module: FPS -> ball query (K nearest within R) -> gather ->
// 3-layer MLP -> masked max aggregation.
//
// B=4 batches, NP=8192 pts, MP=2048 centers/batch, K=64, R=0.2, D_IN=32.
// d_out = [x_out (8192*128) | pos_out (8192*3) | batch_out (8192)] as fp32.
//
// ws layout (bytes):
//   P1  : 0        .. 8388608   (32768 x 64 fp32)  = x @ W1[0:32]
//   W2T : 8388608  .. 8404992   (64x64 fp32, transposed)
//   W3T : 8404992  .. 8437760   (128x64 fp32, transposed)
//   nbr : 8437760  .. 10534912  (8192 x 64 int32, -1 = invalid)

#define BATCH 4
#define NP 8192
#define MP 2048
#define KNN 64
#define DIN 32

// One v_max_f32 + DPP step: disabled/invalid source lanes fall back to `old`
// (= v itself, the fmax identity here).  Pure VALU — no LDS latency.
#define DPP_FMAX(v, ctrl)                                                     \
  {                                                                           \
    int _t = __builtin_amdgcn_update_dpp(__float_as_int(v),                   \
                                         __float_as_int(v), (ctrl), 0xF,      \
                                         0xF, false);                         \
    (v) = fmaxf((v), __int_as_float(_t));                                     \
  }

// float2 ext-vector: clang lowers elementwise ops to v_pk_*_f32 on CDNA
// where profitable and scalarizes otherwise — per-element rounding is
// identical to the scalar form either way (same sub/mul/fma contraction).
typedef float v2f __attribute__((ext_vector_type(2)));

// ---------------------------------------------------------------- FPS ------
// One block per batch, 1024 threads (16 waves), 8 points/thread in VGPRs.
// VALU-issue floor: 8192 pts x 8 ops / (4 SIMD x 32 lanes) = 512 cyc/iter.
// Everything else is kept off the global-memory critical path:
//   - full point table staged ONCE into LDS (96 KB): winner-coordinate
//     fetch is a ~120-cyc uniform ds_read, not a dependent global load.
//   - owner lane stores ONE u64 {d2_bits<<32 | global_idx} per wave slot;
//     stage-2 = one ds_read_b64, 4-step DPP max, ballot->first wid,
//     readlane -> winner idx -> LDS coord fetch.
// Tie-break = first global index, exactly as jnp.argmax: global idx order is
// (wid, lane, k) with j = tid*8+k; ballot-ctz picks first lane, descending
// overwrite picks first k, ballot-ctz on slots picks first wid.
__global__ __launch_bounds__(1024) void fps_k(const float* __restrict__ pos,
                                              float* __restrict__ pout,
                                              float* __restrict__ bout)
{
  const int b = blockIdx.x;
  const int tid = threadIdx.x;
  const int lane = tid & 63, wid = tid >> 6;
  const float* __restrict__ pb = pos + (size_t)b * NP * 3;
  const int base = tid * 8;

  // batch_out as float values (harness reads d_out as one fp32 buffer)
  bout[b * MP + tid] = (float)b;
  bout[b * MP + 1024 + tid] = (float)b;

  __shared__ __align__(16) float ptab[NP * 3];          // 96 KB point table
  __shared__ unsigned long long slt[2][16];             // parity slots

  // --- load 8 points (24 contiguous floats) via 6 float4 loads; stage the
  //     same bits into the LDS table (one-time) and unpack to registers ---
  float t[24];
  const float4* __restrict__ pv = (const float4*)(pb + (size_t)tid * 24);
#pragma unroll
  for (int q = 0; q < 6; q++) *(float4*)&t[q * 4] = pv[q];
#pragma unroll
  for (int q = 0; q < 6; q++) *(float4*)&ptab[tid * 24 + q * 4] = *(float4*)&t[q * 4];

  v2f px[4], py[4], pz[4], d[4];
#pragma unroll
  for (int j = 0; j < 4; j++) {
    px[j].x = t[6 * j + 0]; py[j].x = t[6 * j + 1]; pz[j].x = t[6 * j + 2];
    px[j].y = t[6 * j + 3]; py[j].y = t[6 * j + 4]; pz[j].y = t[6 * j + 5];
  }

  const float c0x = pb[0], c0y = pb[1], c0z = pb[2];
  if (tid == 0) {  // sel[0] = 0
    pout[(size_t)b * MP * 3 + 0] = c0x;
    pout[(size_t)b * MP * 3 + 1] = c0y;
    pout[(size_t)b * MP * 3 + 2] = c0z;
  }

  // initial distances to center 0 (same per-element expression as verified)
  float bv = -1.f;
  {
    v2f cx = {c0x, c0x}, cy = {c0y, c0y}, cz = {c0z, c0z};
#pragma unroll
    for (int j = 0; j < 4; j++) {
      v2f dx = px[j] - cx, dy = py[j] - cy, dz = pz[j] - cz;
      v2f nd = dx * dx + dy * dy + dz * dz;
      d[j] = nd;
      bv = fmaxf(bv, fmaxf(nd.x, nd.y));
    }
  }

  // NOTE: ptab staging is ordered before any ptab read by the i=1 barrier.
  for (int i = 1; i < MP; i++) {
    // --- 64-lane max, pure VALU (DPP): result lands in lane 63 ---
    float v = bv;
    DPP_FMAX(v, 0x111);   // row_shr:1
    DPP_FMAX(v, 0x112);   // row_shr:2
    DPP_FMAX(v, 0x114);   // row_shr:4
    DPP_FMAX(v, 0x118);   // row_shr:8
    DPP_FMAX(v, 0x142);   // row_bcast:15
    DPP_FMAX(v, 0x143);   // row_bcast:31
    const float wmax =
        __int_as_float(__builtin_amdgcn_readlane(__float_as_int(v), 63));

    // owner lane = first lane holding wmax; it writes {value, global idx}
    const unsigned long long m = __ballot(bv == wmax);
    const int src = (int)__builtin_ctzll(m);
    const int p = i & 1;
    if (lane == src) {
      int ks = 7;
#pragma unroll
      for (int k = 6; k >= 0; k--) {         // descending => first k wins
        float dv = (k & 1) ? d[k >> 1].y : d[k >> 1].x;
        if (dv == wmax) ks = k;              // cndmask with inline-const k
      }
      slt[p][wid] = ((unsigned long long)__float_as_uint(wmax) << 32)
                    | (unsigned)(base + ks);
    }
    __syncthreads();

    // --- 16-slot argmax (first-wid tie-break), ONE LDS round trip ---
    const unsigned long long kv = slt[p][lane & 15];   // broadcast reads
    const float v2 = __uint_as_float((unsigned)(kv >> 32));
    float v2r = v2;
    DPP_FMAX(v2r, 0x111);
    DPP_FMAX(v2r, 0x112);
    DPP_FMAX(v2r, 0x114);
    DPP_FMAX(v2r, 0x118);                    // lane 15 = max of slots 0..15
    const float mv =
        __int_as_float(__builtin_amdgcn_readlane(__float_as_int(v2r), 15));
    const unsigned long long m2 = __ballot(v2 == mv);
    const int mw = (int)__builtin_ctzll(m2);           // first wid among ties
    const int js = __builtin_amdgcn_readlane((int)(unsigned)kv, mw);
    // winner coords from the LDS table: uniform-address broadcast reads
    const float ncx = ptab[js * 3 + 0];
    const float ncy = ptab[js * 3 + 1];
    const float ncz = ptab[js * 3 + 2];

    if (tid == 0) {
      pout[((size_t)b * MP + i) * 3 + 0] = ncx;
      pout[((size_t)b * MP + i) * 3 + 1] = ncy;
      pout[((size_t)b * MP + i) * 3 + 2] = ncz;
    }

    // fused min-update + local value max for next iteration
    const v2f cx = {ncx, ncx}, cy = {ncy, ncy}, cz = {ncz, ncz};
    bv = -1.f;
#pragma unroll
    for (int j = 0; j < 4; j++) {
      v2f dx = px[j] - cx, dy = py[j] - cy, dz = pz[j] - cz;
      v2f nd = dx * dx + dy * dy + dz * dz;
      v2f dn;
      dn.x = fminf(d[j].x, nd.x);
      dn.y = fminf(d[j].y, nd.y);
      d[j] = dn;
      bv = fmaxf(bv, fmaxf(dn.x, dn.y));
    }
  }
}

// ---------------------------------------------------------- ball query -----
// One wave (64-thread block) per center. Candidates (d2<=R2) compacted to
// LDS as u64 keys (d2_bits<<32 | idx); 64 rounds of wave-argmin reproduce
// lax.top_k's stable (d2 asc, idx asc) selection exactly.
__global__ __launch_bounds__(64) void ballq_k(const float* __restrict__ pos,
                                              const float* __restrict__ pout,
                                              int* __restrict__ nbr)
{
  const int wg = blockIdx.x;       // center id 0..8191
  const int lane = threadIdx.x;
  const int b = wg >> 11;
  const float* __restrict__ pb = pos + (size_t)b * NP * 3;
  const float cx = pout[(size_t)wg * 3 + 0];
  const float cy = pout[(size_t)wg * 3 + 1];
  const float cz = pout[(size_t)wg * 3 + 2];
  const float R2 = (float)(0.2 * 0.2);   // matches JAX weak-type promotion exactly

  __shared__ unsigned long long cand[1024];
  int cnt = 0;
  for (int basej = 0; basej < NP; basej += 64) {
    const int j = basej + lane;
    float dx = pb[j * 3 + 0] - cx;
    float dy = pb[j * 3 + 1] - cy;
    float dz = pb[j * 3 + 2] - cz;
    float d2 = dx * dx + dy * dy + dz * dz;
    bool in = (d2 <= R2);
    unsigned long long mb = __ballot(in);
    int pre = (int)__popcll(mb & ((1ull << lane) - 1ull));
    int slot = cnt + pre;
    if (in && slot < 1024)
      cand[slot] = ((unsigned long long)__float_as_uint(d2) << 32) | (unsigned int)j;
    cnt += (int)__popcll(mb);
  }
  if (cnt > 1024) cnt = 1024;   // unreachable for this data (max ~360)

  int myout = -1;
  for (int r = 0; r < KNN; r++) {
    unsigned long long v = ~0ull; int slot = -1;
    for (int s = lane; s < cnt; s += 64) {
      unsigned long long c = cand[s];
      if (c < v) { v = c; slot = s; }
    }
#pragma unroll
    for (int off = 1; off < 64; off <<= 1) {
      unsigned long long ov = __shfl_xor(v, off);
      int os = __shfl_xor(slot, off);
      if (ov < v) { v = ov; slot = os; }
    }
    if (lane == r) myout = (v == ~0ull) ? -1 : (int)(v & 0xffffffffu);
    if (lane == 0 && slot >= 0) cand[slot] = ~0ull;  // remove winner
    __syncthreads();
  }
  nbr[(size_t)wg * KNN + lane] = myout;
}

// --------------------------------------------------- P1 = x @ W1[0:32] -----
__global__ __launch_bounds__(64) void p1_k(const float* __restrict__ x,
                                           const float* __restrict__ W1,
                                           float* __restrict__ P1)
{
  const int j = blockIdx.x;          // global point row 0..32767
  const int c = threadIdx.x;
  const float* __restrict__ xr = x + (size_t)j * DIN;
  float acc = 0.f;
#pragma unroll
  for (int k = 0; k < DIN; k++) acc += xr[k] * W1[k * 64 + c];
  P1[(size_t)j * 64 + c] = acc;
}

// ------------------------------------------------------ weight transposes --
__global__ __launch_bounds__(256) void tw_k(const float* __restrict__ W2,
                                            const float* __restrict__ W3,
                                            float* __restrict__ W2T,
                                            float* __restrict__ W3T)
{
  int e = blockIdx.x * 256 + threadIdx.x;
  if (e < 64 * 64) {
    int c = e >> 6, k = e & 63;
    W2T[e] = W2[k * 64 + c];
  } else {
    int e2 = e - 64 * 64;
    if (e2 < 128 * 64) {
      int c = e2 >> 6, k = e2 & 63;
      W3T[e2] = W3[k * 128 + c];
    }
  }
}

// ------------------------------------------------------- MLP + max agg -----
// One wave (64-thread block) per center, lane = neighbor slot.
// h1 in VGPRs; h2 staged in LDS at stride 68 floats (stride 64 => 64-way
// bank conflict; 68 => conflict-free b128 pattern). Weight reads use
// wave-uniform indices -> scalar (SGPR) loads.
__global__ __launch_bounds__(64) void mlp_k(const float* __restrict__ pos,
    const float* __restrict__ P1, const float* __restrict__ W1,
    const float* __restrict__ b1, const float* __restrict__ W2T,
    const float* __restrict__ b2, const float* __restrict__ W3T,
    const float* __restrict__ b3, const int* __restrict__ nbr,
    const float* __restrict__ pout, float* __restrict__ xout)
{
  __shared__ __align__(16) float h2s[64 * 68];
  const int wg = blockIdx.x;
  const int lane = threadIdx.x;
  const int b = wg >> 11;
  const int idx = nbr[(size_t)wg * KNN + lane];
  const bool valid = idx >= 0;
  const int j = valid ? idx : 0;
  const float cx = pout[(size_t)wg * 3 + 0];
  const float cy = pout[(size_t)wg * 3 + 1];
  const float cz = pout[(size_t)wg * 3 + 2];
  const float* __restrict__ pj = pos + ((size_t)b * NP + j) * 3;
  const float rx = pj[0] - cx, ry = pj[1] - cy, rz = pj[2] - cz;
  const float* __restrict__ p1r =
      (const float*)__builtin_assume_aligned(P1 + ((size_t)b * NP + j) * 64, 16);

  // layer 1: h1 = relu(P1[j] + rel @ W1[32:35] + b1)   (64 VGPRs)
  float h1[64];
#pragma unroll
  for (int k = 0; k < 64; k++) {
    float v = p1r[k] + rx * W1[32 * 64 + k] + ry * W1[33 * 64 + k]
                     + rz * W1[34 * 64 + k] + b1[k];
    h1[k] = fmaxf(v, 0.f);
  }

  // layer 2: h2 = relu(h1 @ W2 + b2) -> LDS
  for (int c4 = 0; c4 < 16; c4++) {
    float a0 = b2[c4 * 4 + 0], a1 = b2[c4 * 4 + 1];
    float a2 = b2[c4 * 4 + 2], a3 = b2[c4 * 4 + 3];
    const float* __restrict__ w0 = W2T + (c4 * 4 + 0) * 64;
    const float* __restrict__ w1 = W2T + (c4 * 4 + 1) * 64;
    const float* __restrict__ w2 = W2T + (c4 * 4 + 2) * 64;
    const float* __restrict__ w3 = W2T + (c4 * 4 + 3) * 64;
#pragma unroll
    for (int k = 0; k < 64; k++) {
      a0 += h1[k] * w0[k]; a1 += h1[k] * w1[k];
      a2 += h1[k] * w2[k]; a3 += h1[k] * w3[k];
    }
    float4 q;
    q.x = fmaxf(a0, 0.f); q.y = fmaxf(a1, 0.f);
    q.z = fmaxf(a2, 0.f); q.w = fmaxf(a3, 0.f);
    *(float4*)&h2s[lane * 68 + c4 * 4] = q;
  }

  // layer 3 + per-channel max over neighbors (relu>=0 and center is always a
  // valid neighbor, so invalid lanes contributing 0 == reference -BIG mask)
  float4 keep = make_float4(0.f, 0.f, 0.f, 0.f);
  const float* __restrict__ h2p = &h2s[lane * 68];
  for (int c4 = 0; c4 < 32; c4++) {
    float a0 = b3[c4 * 4 + 0], a1 = b3[c4 * 4 + 1];
    float a2 = b3[c4 * 4 + 2], a3 = b3[c4 * 4 + 3];
    const float* __restrict__ w0 = W3T + (c4 * 4 + 0) * 64;
    const float* __restrict__ w1 = W3T + (c4 * 4 + 1) * 64;
    const float* __restrict__ w2 = W3T + (c4 * 4 + 2) * 64;
    const float* __restrict__ w3 = W3T + (c4 * 4 + 3) * 64;
#pragma unroll
    for (int k4 = 0; k4 < 16; k4++) {
      float4 h = *(const float4*)&h2p[k4 * 4];
      a0 += h.x * w0[k4 * 4 + 0]; a0 += h.y * w0[k4 * 4 + 1];
      a0 += h.z * w0[k4 * 4 + 2]; a0 += h.w * w0[k4 * 4 + 3];
      a1 += h.x * w1[k4 * 4 + 0]; a1 += h.y * w1[k4 * 4 + 1];
      a1 += h.z * w1[k4 * 4 + 2]; a1 += h.w * w1[k4 * 4 + 3];
      a2 += h.x * w2[k4 * 4 + 0]; a2 += h.y * w2[k4 * 4 + 1];
      a2 += h.z * w2[k4 * 4 + 2]; a2 += h.w * w2[k4 * 4 + 3];
      a3 += h.x * w3[k4 * 4 + 0]; a3 += h.y * w3[k4 * 4 + 1];
      a3 += h.z * w3[k4 * 4 + 2]; a3 += h.w * w3[k4 * 4 + 3];
    }
    a0 = valid ? fmaxf(a0, 0.f) : 0.f;
    a1 = valid ? fmaxf(a1, 0.f) : 0.f;
    a2 = valid ? fmaxf(a2, 0.f) : 0.f;
    a3 = valid ? fmaxf(a3, 0.f) : 0.f;
#pragma unroll
    for (int off = 1; off < 64; off <<= 1) {
      a0 = fmaxf(a0, __shfl_xor(a0, off));
      a1 = fmaxf(a1, __shfl_xor(a1, off));
      a2 = fmaxf(a2, __shfl_xor(a2, off));
      a3 = fmaxf(a3, __shfl_xor(a3, off));
    }
    if (lane == c4) { keep.x = a0; keep.y = a1; keep.z = a2; keep.w = a3; }
  }
  if (lane < 32)
    *(float4*)&xout[(size_t)wg * 128 + lane * 4] = keep;
}

// --------------------------------------------------------------- launch ----
extern "C" void kernel_launch(void* const* d_in, const int* in_sizes, int n_in,
                              void* d_out, int out_size, void* d_ws, size_t ws_size,
                              hipStream_t stream)
{
  const float* x   = (const float*)d_in[0];
  const float* pos = (const float*)d_in[1];
  // d_in[2] = batch (unused; layout is implicit)
  const float* W1 = (const float*)d_in[3];
  const float* b1 = (const float*)d_in[4];
  const float* W2 = (const float*)d_in[5];
  const float* b2 = (const float*)d_in[6];
  const float* W3 = (const float*)d_in[7];
  const float* b3 = (const float*)d_in[8];

  float* out  = (float*)d_out;
  float* xout = out;                      // 8192*128
  float* pout = out + 8192 * 128;         // 8192*3
  float* bout = out + 8192 * 128 + 8192 * 3;  // 8192

  char* ws = (char*)d_ws;
  float* P1  = (float*)ws;
  float* W2T = (float*)(ws + 8388608);
  float* W3T = (float*)(ws + 8404992);
  int*   nbr = (int*)(ws + 8437760);

  fps_k<<<dim3(BATCH), dim3(1024), 0, stream>>>(pos, pout, bout);
  p1_k<<<dim3(BATCH * NP), dim3(64), 0, stream>>>(x, W1, P1);
  tw_k<<<dim3(48), dim3(256), 0, stream>>>(W2, W3, W2T, W3T);
  ballq_k<<<dim3(BATCH * MP), dim3(64), 0, stream>>>(pos, pout, nbr);
  mlp_k<<<dim3(BATCH * MP), dim3(64), 0, stream>>>(pos, P1, W1, b1, W2T, b2,
                                                   W3T, b3, nbr, pout, xout);
}